// Round 6
// baseline (76.390 us; speedup 1.0000x reference)
//
#include <hip/hip_runtime.h>

// myAttention: B=1M batches, D=16, T=4.
// x=[16,4] per batch (cols = inputs), M = x^T x (4x4),
// att = softmax over rows (axis=1, per-column norm),
// out[d] = sum_i x[d][i]*w[i], w[i] = sum_j att[i][j].
//
// R5 (quad-per-batch + NT stores): 62 us. VALU time ~35 us (214 instr/thread,
// 4x-redundant softmax + 2-level quad reduce) vs ~40 us memory -> VALU-heavy.
// R6: PAIR-PER-BATCH. 2 threads/batch, thread h owns 8 features. Per-batch
// VALU -42% (softmax redundancy 4x->2x, reduce 2 levels->1, addressing /2).
// Loads/stores: 16B per lane at 32B stride; the v=0/v=1 instruction pair
// covers complementary halves of the same cache lines -> same HBM traffic.

typedef float v4f __attribute__((ext_vector_type(4)));

__global__ __launch_bounds__(256) void myattn_kernel(
    const float* __restrict__ in0, const float* __restrict__ in1,
    const float* __restrict__ in2, const float* __restrict__ in3,
    float* __restrict__ out, float* __restrict__ att_out, int B)
{
    int t = blockIdx.x * blockDim.x + threadIdx.x;   // [0, 2*B)
    int b = t >> 1;                                   // batch
    if (b >= B) return;
    size_t fbase = (size_t)t * 8;                     // floats: b*16 + h*8

    // Thread h owns features h*8 .. h*8+7 of all 4 inputs (8 x 16B loads).
    v4f xq[4][2];
    xq[0][0] = *reinterpret_cast<const v4f*>(in0 + fbase);
    xq[0][1] = *reinterpret_cast<const v4f*>(in0 + fbase + 4);
    xq[1][0] = *reinterpret_cast<const v4f*>(in1 + fbase);
    xq[1][1] = *reinterpret_cast<const v4f*>(in1 + fbase + 4);
    xq[2][0] = *reinterpret_cast<const v4f*>(in2 + fbase);
    xq[2][1] = *reinterpret_cast<const v4f*>(in2 + fbase + 4);
    xq[3][0] = *reinterpret_cast<const v4f*>(in3 + fbase);
    xq[3][1] = *reinterpret_cast<const v4f*>(in3 + fbase + 4);

    // Partial M over this thread's 8 features, one-level pair reduce.
    float M[4][4];
    #pragma unroll
    for (int i = 0; i < 4; ++i) {
        #pragma unroll
        for (int j = i; j < 4; ++j) {
            float s = xq[i][0][0] * xq[j][0][0];
            #pragma unroll
            for (int k = 0; k < 2; ++k)
                #pragma unroll
                for (int c = 0; c < 4; ++c)
                    if (k || c) s = fmaf(xq[i][k][c], xq[j][k][c], s);
            s += __shfl_xor(s, 1);   // partner = other half of same batch
            M[i][j] = s;
            M[j][i] = s;
        }
    }

    // softmax over axis=1 (rows i), per column j — redundant x2 per batch
    float att[4][4];
    #pragma unroll
    for (int j = 0; j < 4; ++j) {
        float m = fmaxf(fmaxf(M[0][j], M[1][j]), fmaxf(M[2][j], M[3][j]));
        float e0 = __expf(M[0][j] - m);
        float e1 = __expf(M[1][j] - m);
        float e2 = __expf(M[2][j] - m);
        float e3 = __expf(M[3][j] - m);
        float inv = 1.f / (e0 + e1 + e2 + e3);
        att[0][j] = e0 * inv;
        att[1][j] = e1 * inv;
        att[2][j] = e2 * inv;
        att[3][j] = e3 * inv;
    }

    // w[i] = sum_j att[i][j]
    float w[4];
    #pragma unroll
    for (int i = 0; i < 4; ++i)
        w[i] = att[i][0] + att[i][1] + att[i][2] + att[i][3];

    // out slice: 8 features
    v4f o0, o1;
    #pragma unroll
    for (int c = 0; c < 4; ++c) {
        o0[c] = fmaf(xq[0][0][c], w[0], fmaf(xq[1][0][c], w[1],
                fmaf(xq[2][0][c], w[2], xq[3][0][c] * w[3])));
        o1[c] = fmaf(xq[0][1][c], w[0], fmaf(xq[1][1][c], w[1],
                fmaf(xq[2][1][c], w[2], xq[3][1][c] * w[3])));
    }
    __builtin_nontemporal_store(o0, reinterpret_cast<v4f*>(out + fbase));
    __builtin_nontemporal_store(o1, reinterpret_cast<v4f*>(out + fbase + 4));

    // att rows 2h and 2h+1 -> floats b*16 + h*8 .. +7 == fbase. Coalesced.
    bool hi = (t & 1);
    v4f a0, a1;
    #pragma unroll
    for (int j = 0; j < 4; ++j) {
        a0[j] = hi ? att[2][j] : att[0][j];
        a1[j] = hi ? att[3][j] : att[1][j];
    }
    __builtin_nontemporal_store(a0, reinterpret_cast<v4f*>(att_out + fbase));
    __builtin_nontemporal_store(a1, reinterpret_cast<v4f*>(att_out + fbase + 4));
}

extern "C" void kernel_launch(void* const* d_in, const int* in_sizes, int n_in,
                              void* d_out, int out_size, void* d_ws, size_t ws_size,
                              hipStream_t stream) {
    int B = in_sizes[0] / 16;
    const float* in0 = (const float*)d_in[0];
    const float* in1 = (const float*)d_in[1];
    const float* in2 = (const float*)d_in[2];
    const float* in3 = (const float*)d_in[3];
    float* out = (float*)d_out;
    float* att = out + (size_t)B * 16;

    const int threads = 256;
    const long long total = 2LL * B;
    const int blocks = (int)((total + threads - 1) / threads);
    myattn_kernel<<<blocks, threads, 0, stream>>>(in0, in1, in2, in3, out, att, B);
}

// Round 7
// 72.181 us; speedup vs baseline: 1.0583x; 1.0583x over previous
//
#include <hip/hip_runtime.h>

// myAttention: B=1M batches, D=16, T=4.
// x=[16,4] per batch (cols = inputs), M = x^T x (4x4),
// att = softmax over rows (axis=1, per-column norm),
// out[d] = sum_i x[d][i]*w[i], w[i] = sum_j att[i][j].
//
// R5 (quad-per-batch + NT stores): 62 us. Read-MLP bound: 4x16B loads/thread
// -> ~1.5KB in flight per CU vs ~9KB needed (Little's law) -> fetch 2.3 TB/s.
// R6 (pair-per-batch) regressed ONLY because the compiler demoted xq[4][2]
// to LDS (LDS_Block_Size=16384, 5.5M bank conflicts) - codegen trap, not the
// memory pattern.
// R7: TWO BATCHES PER THREAD, quad-per-batch within (8 loads in flight,
// 2x read MLP), R4-proven register-clean code style (no conditional loops,
// scalar-named loads). Softmax: batch-global max + symmetric E (10 exps not
// 16; shift-invariance holds for a global shift; max diag ~65 << 88 so no
// overflow, denom >= e^-gm so no underflow). NT stores kept.

typedef float v4f __attribute__((ext_vector_type(4)));

__device__ __forceinline__ void process_batch(
    v4f x0, v4f x1, v4f x2, v4f x3, int e,
    float* __restrict__ outp, float* __restrict__ attp)
{
    v4f xq[4] = {x0, x1, x2, x3};

    // M[i][j] = sum_d x[i][d]*x[j][d], quad-reduced (10 uniques)
    float M[4][4];
    #pragma unroll
    for (int i = 0; i < 4; ++i) {
        #pragma unroll
        for (int j = i; j < 4; ++j) {
            float s = xq[i][0] * xq[j][0];
            s = fmaf(xq[i][1], xq[j][1], s);
            s = fmaf(xq[i][2], xq[j][2], s);
            s = fmaf(xq[i][3], xq[j][3], s);
            s += __shfl_xor(s, 1);
            s += __shfl_xor(s, 2);
            M[i][j] = s;
            M[j][i] = s;
        }
    }

    // batch-global max over the 10 uniques (valid shift for every column)
    float gm = fmaxf(fmaxf(M[0][0], M[1][1]), fmaxf(M[2][2], M[3][3]));
    gm = fmaxf(gm, fmaxf(fmaxf(M[0][1], M[0][2]), fmaxf(M[0][3], M[1][2])));
    gm = fmaxf(gm, fmaxf(M[1][3], M[2][3]));

    // E = exp(M - gm), symmetric: 10 exps
    float E[4][4];
    #pragma unroll
    for (int i = 0; i < 4; ++i) {
        #pragma unroll
        for (int j = i; j < 4; ++j) {
            float v = __expf(M[i][j] - gm);
            E[i][j] = v;
            E[j][i] = v;
        }
    }

    // per-column inverse sums
    float inv[4];
    #pragma unroll
    for (int j = 0; j < 4; ++j)
        inv[j] = 1.f / (E[0][j] + E[1][j] + E[2][j] + E[3][j]);

    // w[i] = sum_j att[i][j] = sum_j E[i][j]*inv[j]
    float w[4];
    #pragma unroll
    for (int i = 0; i < 4; ++i)
        w[i] = fmaf(E[i][0], inv[0], fmaf(E[i][1], inv[1],
               fmaf(E[i][2], inv[2], E[i][3] * inv[3])));

    // out slice: out[4e+k] = sum_i x[i][4e+k]*w[i]
    v4f o;
    #pragma unroll
    for (int k = 0; k < 4; ++k)
        o[k] = fmaf(xq[0][k], w[0], fmaf(xq[1][k], w[1],
               fmaf(xq[2][k], w[2], xq[3][k] * w[3])));
    __builtin_nontemporal_store(o, reinterpret_cast<v4f*>(outp));

    // att row e: att[e][j] = E[e][j]*inv[j]
    v4f a;
    #pragma unroll
    for (int j = 0; j < 4; ++j)
        a[j] = E[e][j] * inv[j];
    __builtin_nontemporal_store(a, reinterpret_cast<v4f*>(attp));
}

__global__ __launch_bounds__(256) void myattn_kernel(
    const float* __restrict__ in0, const float* __restrict__ in1,
    const float* __restrict__ in2, const float* __restrict__ in3,
    float* __restrict__ out, float* __restrict__ att_out, int Bhalf)
{
    int t = blockIdx.x * blockDim.x + threadIdx.x;   // [0, 4*Bhalf)
    int g = t >> 2;                                   // batch-pair index
    int e = t & 3;                                    // quad slot (features 4e..4e+3)
    if (g >= Bhalf) return;
    size_t fA = (size_t)g * 32 + (size_t)e * 4;       // batch 2g,   floats
    size_t fB = fA + 16;                              // batch 2g+1, floats

    // Issue all 8 loads up front: 2x read MLP vs R5.
    v4f a0 = *reinterpret_cast<const v4f*>(in0 + fA);
    v4f b0 = *reinterpret_cast<const v4f*>(in0 + fB);
    v4f a1 = *reinterpret_cast<const v4f*>(in1 + fA);
    v4f b1 = *reinterpret_cast<const v4f*>(in1 + fB);
    v4f a2 = *reinterpret_cast<const v4f*>(in2 + fA);
    v4f b2 = *reinterpret_cast<const v4f*>(in2 + fB);
    v4f a3 = *reinterpret_cast<const v4f*>(in3 + fA);
    v4f b3 = *reinterpret_cast<const v4f*>(in3 + fB);

    process_batch(a0, a1, a2, a3, e, out + fA, att_out + fA);
    process_batch(b0, b1, b2, b3, e, out + fB, att_out + fB);
}

extern "C" void kernel_launch(void* const* d_in, const int* in_sizes, int n_in,
                              void* d_out, int out_size, void* d_ws, size_t ws_size,
                              hipStream_t stream) {
    int B = in_sizes[0] / 16;
    int Bhalf = B / 2;
    const float* in0 = (const float*)d_in[0];
    const float* in1 = (const float*)d_in[1];
    const float* in2 = (const float*)d_in[2];
    const float* in3 = (const float*)d_in[3];
    float* out = (float*)d_out;
    float* att = out + (size_t)B * 16;

    const int threads = 256;
    const long long total = 4LL * Bhalf;
    const int blocks = (int)((total + threads - 1) / threads);
    myattn_kernel<<<blocks, threads, 0, stream>>>(in0, in1, in2, in3, out, att, Bhalf);
}

// Round 8
// 68.613 us; speedup vs baseline: 1.1133x; 1.0520x over previous
//
#include <hip/hip_runtime.h>

// myAttention: B=1M batches, D=16, T=4.
// x=[16,4] per batch (cols = inputs), M = x^T x (4x4),
// att = softmax over rows (axis=1, per-column norm),
// out[d] = sum_i x[d][i]*w[i], w[i] = sum_j att[i][j].
//
// R5 (quad-per-batch + NT stores): 62 us, ~4.3 TB/s HBM-side vs 6.3 ceiling.
// R7 (2 batches/thread) failed: compiler sank the 2nd batch's loads
// (VGPR stuck at 32) -> no MLP gain, half the waves -> 72 us.
// R8: same 2-batches-per-thread, but an empty asm with "+v" on all 8 loaded
// vectors FORCES all 8 global_load_dwordx4 to be in flight simultaneously
// (one waitcnt, then ~900cy of compute). VGPR target ~56 (<=64 keeps
// 8 waves/SIMD). Batch pair shares one voffset; +64B is an imm offset.

typedef float v4f __attribute__((ext_vector_type(4)));

__device__ __forceinline__ void process_batch(
    v4f x0, v4f x1, v4f x2, v4f x3, int e,
    float* __restrict__ outp, float* __restrict__ attp)
{
    v4f xq[4] = {x0, x1, x2, x3};

    // M[i][j] = sum_d x[i][d]*x[j][d], quad-reduced (10 uniques)
    float M[4][4];
    #pragma unroll
    for (int i = 0; i < 4; ++i) {
        #pragma unroll
        for (int j = i; j < 4; ++j) {
            float s = xq[i][0] * xq[j][0];
            s = fmaf(xq[i][1], xq[j][1], s);
            s = fmaf(xq[i][2], xq[j][2], s);
            s = fmaf(xq[i][3], xq[j][3], s);
            s += __shfl_xor(s, 1);
            s += __shfl_xor(s, 2);
            M[i][j] = s;
            M[j][i] = s;
        }
    }

    // batch-global max (valid shift for every column)
    float gm = fmaxf(fmaxf(M[0][0], M[1][1]), fmaxf(M[2][2], M[3][3]));
    gm = fmaxf(gm, fmaxf(fmaxf(M[0][1], M[0][2]), fmaxf(M[0][3], M[1][2])));
    gm = fmaxf(gm, fmaxf(M[1][3], M[2][3]));

    // E = exp(M - gm), symmetric: 10 exps
    float E[4][4];
    #pragma unroll
    for (int i = 0; i < 4; ++i) {
        #pragma unroll
        for (int j = i; j < 4; ++j) {
            float v = __expf(M[i][j] - gm);
            E[i][j] = v;
            E[j][i] = v;
        }
    }

    // per-column inverse sums
    float inv[4];
    #pragma unroll
    for (int j = 0; j < 4; ++j)
        inv[j] = 1.f / (E[0][j] + E[1][j] + E[2][j] + E[3][j]);

    // w[i] = sum_j E[i][j]*inv[j]
    float w[4];
    #pragma unroll
    for (int i = 0; i < 4; ++i)
        w[i] = fmaf(E[i][0], inv[0], fmaf(E[i][1], inv[1],
               fmaf(E[i][2], inv[2], E[i][3] * inv[3])));

    // out slice: out[4e+k] = sum_i x[i][4e+k]*w[i]
    v4f o;
    #pragma unroll
    for (int k = 0; k < 4; ++k)
        o[k] = fmaf(xq[0][k], w[0], fmaf(xq[1][k], w[1],
               fmaf(xq[2][k], w[2], xq[3][k] * w[3])));
    __builtin_nontemporal_store(o, reinterpret_cast<v4f*>(outp));

    // att row e: att[e][j] = E[e][j]*inv[j]
    v4f a;
    #pragma unroll
    for (int j = 0; j < 4; ++j)
        a[j] = E[e][j] * inv[j];
    __builtin_nontemporal_store(a, reinterpret_cast<v4f*>(attp));
}

__global__ __launch_bounds__(256) void myattn_kernel(
    const float* __restrict__ in0, const float* __restrict__ in1,
    const float* __restrict__ in2, const float* __restrict__ in3,
    float* __restrict__ out, float* __restrict__ att_out, int Bhalf)
{
    int t = blockIdx.x * blockDim.x + threadIdx.x;   // [0, 4*Bhalf)
    int g = t >> 2;                                   // batch-pair index
    int e = t & 3;                                    // quad slot (features 4e..4e+3)
    if (g >= Bhalf) return;
    size_t fA = (size_t)g * 32 + (size_t)e * 4;       // batch 2g   (floats)
    size_t fB = fA + 16;                              // batch 2g+1 (floats)

    // Issue all 8 loads; pairs share a voffset (+64B imm for B).
    v4f a0 = *reinterpret_cast<const v4f*>(in0 + fA);
    v4f b0 = *reinterpret_cast<const v4f*>(in0 + fB);
    v4f a1 = *reinterpret_cast<const v4f*>(in1 + fA);
    v4f b1 = *reinterpret_cast<const v4f*>(in1 + fB);
    v4f a2 = *reinterpret_cast<const v4f*>(in2 + fA);
    v4f b2 = *reinterpret_cast<const v4f*>(in2 + fB);
    v4f a3 = *reinterpret_cast<const v4f*>(in3 + fA);
    v4f b3 = *reinterpret_cast<const v4f*>(in3 + fB);

    // Pin: all 8 results must be live in VGPRs here -> 8 loads in flight,
    // one waitcnt, then pure compute. Prevents the R7 load-sinking.
    asm volatile("" : "+v"(a0), "+v"(a1), "+v"(a2), "+v"(a3),
                      "+v"(b0), "+v"(b1), "+v"(b2), "+v"(b3));

    process_batch(a0, a1, a2, a3, e, out + fA, att_out + fA);
    process_batch(b0, b1, b2, b3, e, out + fB, att_out + fB);
}

extern "C" void kernel_launch(void* const* d_in, const int* in_sizes, int n_in,
                              void* d_out, int out_size, void* d_ws, size_t ws_size,
                              hipStream_t stream) {
    int B = in_sizes[0] / 16;
    int Bhalf = B / 2;
    const float* in0 = (const float*)d_in[0];
    const float* in1 = (const float*)d_in[1];
    const float* in2 = (const float*)d_in[2];
    const float* in3 = (const float*)d_in[3];
    float* out = (float*)d_out;
    float* att = out + (size_t)B * 16;

    const int threads = 256;
    const long long total = 4LL * Bhalf;
    const int blocks = (int)((total + threads - 1) / threads);
    myattn_kernel<<<blocks, threads, 0, stream>>>(in0, in1, in2, in3, out, att, Bhalf);
}

// Round 9
// 62.429 us; speedup vs baseline: 1.2236x; 1.0991x over previous
//
#include <hip/hip_runtime.h>

// myAttention: B=1M batches, D=16, T=4.
// x=[16,4] per batch (cols = inputs), M = x^T x (4x4),
// att = softmax over rows (axis=1, per-column norm),
// out[d] = sum_i x[d][i]*w[i], w[i] = sum_j att[i][j].
//
// Best = R5 structure: quad-per-batch (4 threads/batch, thread e owns
// features 4e..4e+3), perfectly coalesced 16B/lane loads+stores, NT stores.
// 62 us = 402 MB logical / 62 us = 6.5 TB/s logical — above the 6.3 TB/s
// copy ceiling thanks to ~50% L3 input residency. Pure-HBM floor is 64 us.
// R7/R8 showed multi-batch-per-thread only hurts (halves waves, perturbs
// store stream; MLP was never the limiter — 4 loads x 24+ waves/CU is
// already ~100KB in flight vs ~9KB needed).
// R9 = R5 + the validated global-max 10-exp symmetric softmax (fewer VALU).

typedef float v4f __attribute__((ext_vector_type(4)));

__global__ __launch_bounds__(256) void myattn_kernel(
    const float* __restrict__ in0, const float* __restrict__ in1,
    const float* __restrict__ in2, const float* __restrict__ in3,
    float* __restrict__ out, float* __restrict__ att_out, int B)
{
    int t = blockIdx.x * blockDim.x + threadIdx.x;   // [0, 4*B)
    int b = t >> 2;                                   // batch
    if (b >= B) return;
    size_t fbase = (size_t)t * 4;                     // float offset = b*16 + e*4

    // Each thread: one float4 per input (features 4e..4e+3). Coalesced.
    v4f xq[4];
    xq[0] = *reinterpret_cast<const v4f*>(in0 + fbase);
    xq[1] = *reinterpret_cast<const v4f*>(in1 + fbase);
    xq[2] = *reinterpret_cast<const v4f*>(in2 + fbase);
    xq[3] = *reinterpret_cast<const v4f*>(in3 + fbase);

    // Partial M over this thread's 4 features, quad butterfly-reduce (DPP).
    float M[4][4];
    #pragma unroll
    for (int i = 0; i < 4; ++i) {
        #pragma unroll
        for (int j = i; j < 4; ++j) {
            float s = xq[i][0] * xq[j][0];
            s = fmaf(xq[i][1], xq[j][1], s);
            s = fmaf(xq[i][2], xq[j][2], s);
            s = fmaf(xq[i][3], xq[j][3], s);
            s += __shfl_xor(s, 1);
            s += __shfl_xor(s, 2);
            M[i][j] = s;
            M[j][i] = s;
        }
    }

    // Batch-global max (a valid shift for every column; diag max ~65 << 88
    // so exp never overflows, denom >= e^-gm so never 0).
    float gm = fmaxf(fmaxf(M[0][0], M[1][1]), fmaxf(M[2][2], M[3][3]));
    gm = fmaxf(gm, fmaxf(fmaxf(M[0][1], M[0][2]), fmaxf(M[0][3], M[1][2])));
    gm = fmaxf(gm, fmaxf(M[1][3], M[2][3]));

    // E = exp(M - gm), symmetric: 10 exps (not 16).
    float E[4][4];
    #pragma unroll
    for (int i = 0; i < 4; ++i) {
        #pragma unroll
        for (int j = i; j < 4; ++j) {
            float v = __expf(M[i][j] - gm);
            E[i][j] = v;
            E[j][i] = v;
        }
    }

    // Per-column inverse sums.
    float inv[4];
    #pragma unroll
    for (int j = 0; j < 4; ++j)
        inv[j] = 1.f / (E[0][j] + E[1][j] + E[2][j] + E[3][j]);

    // w[i] = sum_j att[i][j] = sum_j E[i][j]*inv[j]
    float w[4];
    #pragma unroll
    for (int i = 0; i < 4; ++i)
        w[i] = fmaf(E[i][0], inv[0], fmaf(E[i][1], inv[1],
               fmaf(E[i][2], inv[2], E[i][3] * inv[3])));

    // out slice: out[4e+k] = sum_i x[i][4e+k]*w[i]
    v4f o;
    #pragma unroll
    for (int k = 0; k < 4; ++k)
        o[k] = fmaf(xq[0][k], w[0], fmaf(xq[1][k], w[1],
               fmaf(xq[2][k], w[2], xq[3][k] * w[3])));
    __builtin_nontemporal_store(o, reinterpret_cast<v4f*>(out + fbase));

    // att output [B,4,4] row-major: thread e stores row i=e at fbase.
    int e = t & 3;
    v4f a;
    #pragma unroll
    for (int j = 0; j < 4; ++j)
        a[j] = E[e][j] * inv[j];
    __builtin_nontemporal_store(a, reinterpret_cast<v4f*>(att_out + fbase));
}

extern "C" void kernel_launch(void* const* d_in, const int* in_sizes, int n_in,
                              void* d_out, int out_size, void* d_ws, size_t ws_size,
                              hipStream_t stream) {
    int B = in_sizes[0] / 16;
    const float* in0 = (const float*)d_in[0];
    const float* in1 = (const float*)d_in[1];
    const float* in2 = (const float*)d_in[2];
    const float* in3 = (const float*)d_in[3];
    float* out = (float*)d_out;
    float* att = out + (size_t)B * 16;

    const int threads = 256;
    const long long total = 4LL * B;
    const int blocks = (int)((total + threads - 1) / threads);
    myattn_kernel<<<blocks, threads, 0, stream>>>(in0, in1, in2, in3, out, att, B);
}